// Round 10
// baseline (1999.199 us; speedup 1.0000x reference)
//
#include <hip/hip_runtime.h>

#define T_   128
#define B_   256
#define C_   512
#define H_   512
#define L_   26
#define NCLS 6736
#define NPAD 6784   // 53*128, padded N for final GEMM

typedef __attribute__((ext_vector_type(8))) short short8;
typedef __attribute__((ext_vector_type(4))) float f32x4;

__device__ __forceinline__ unsigned short f2b(float f) {
    union { float f; unsigned int u; } v; v.f = f;
    unsigned int r = (v.u + 0x7fffu + ((v.u >> 16) & 1u)) >> 16;
    return (unsigned short)r;
}
__device__ __forceinline__ float b2f(unsigned short u) {
    union { unsigned int u; float f; } v; v.u = ((unsigned int)u) << 16;
    return v.f;
}
__device__ __forceinline__ float tanh_fast(float x) {
    float e = __expf(2.f * x);
    return 1.f - 2.f / (e + 1.f);
}
__device__ __forceinline__ float sigm(float x) {
    return 1.f / (1.f + __expf(-x));
}
__device__ __forceinline__ void llds16(const unsigned short* g, unsigned short* l) {
    __builtin_amdgcn_global_load_lds(
        (const __attribute__((address_space(1))) void*)g,
        (__attribute__((address_space(3))) void*)l, 16, 0, 0);
}

// ---------------- prep: casts + zero-init h ----------------
__global__ __launch_bounds__(256) void prep_kernel(
    const float* __restrict__ feats, const float* __restrict__ W_i2h,
    const float* __restrict__ W_gen, const float* __restrict__ W_h2h,
    const float* __restrict__ W_hh, const float* __restrict__ W_ih,
    unsigned short* __restrict__ feats16, unsigned short* __restrict__ wi2h16,
    unsigned short* __restrict__ wgen16, unsigned short* __restrict__ w1_16,
    unsigned short* __restrict__ wih16,
    float* __restrict__ h32, unsigned short* __restrict__ h16)
{
    size_t idx = (size_t)blockIdx.x * 256 + threadIdx.x;   // 16,777,216 total
    feats16[idx] = f2b(feats[idx]);
    if (idx < (size_t)H_ * C_) wi2h16[idx] = f2b(W_i2h[idx]);
    if (idx < (size_t)NPAD * H_)
        wgen16[idx] = (idx < (size_t)NCLS * H_) ? f2b(W_gen[idx]) : (unsigned short)0;
    if (idx < (size_t)2048 * 512)
        w1_16[idx] = f2b(idx < 262144 ? W_h2h[idx] : W_hh[idx - 262144]);
    if (idx < (size_t)1536 * 512) wih16[idx] = f2b(W_ih[idx]);
    if (idx < (size_t)B_ * H_) { h32[idx] = 0.f; h16[idx] = 0; }
}

// ---------------- bf16 MFMA GEMM, C = A @ B^T (+bias), XCD swizzle ----------------
template<int OUTMODE>   // 0: bf16 out (ld=N)  1: f32 out + bias + col<ncols guard (ld=ncols)
__global__ __launch_bounds__(256) void gemm_bt(
    const unsigned short* __restrict__ A, const unsigned short* __restrict__ B,
    void* __restrict__ outp, const float* __restrict__ bias,
    int M, int N, int K, int ncols)
{
    __shared__ unsigned short As[128 * 32];
    __shared__ unsigned short Bs[128 * 32];
    const int tid = threadIdx.x;
    const int lane = tid & 63;

    const int gridN = (int)gridDim.x, gridM = (int)gridDim.y;
    const int bid = (int)blockIdx.y * gridN + (int)blockIdx.x;
    const int GM = 8;
    const int per = GM * gridN;
    const int grp = bid / per;
    const int rem = bid - grp * per;
    const int gsz0 = gridM - grp * GM;
    const int gsz = gsz0 < GM ? gsz0 : GM;
    const int m0 = (grp * GM + rem % gsz) * 128;
    const int n0 = (rem / gsz) * 128;

    const int wv = tid >> 6;
    const int wm = (wv >> 1) * 64;
    const int wn = (wv & 1) * 64;

    f32x4 acc[4][4];
#pragma unroll
    for (int i = 0; i < 4; i++)
#pragma unroll
        for (int j = 0; j < 4; j++) acc[i][j] = (f32x4)0.f;

    for (int k0 = 0; k0 < K; k0 += 32) {
        __syncthreads();
#pragma unroll
        for (int is = 0; is < 2; ++is) {
            int c = is * 256 + tid;
            int row = c >> 2, col = (c & 3) * 8;
            llds16(A + (size_t)(m0 + row) * K + k0 + col, &As[c * 8]);
            llds16(B + (size_t)(n0 + row) * K + k0 + col, &Bs[c * 8]);
        }
        __syncthreads();
        short8 af[4], bf[4];
#pragma unroll
        for (int t = 0; t < 4; t++) {
            af[t] = *(const short8*)&As[(wm + t * 16 + (lane & 15)) * 32 + (lane >> 4) * 8];
            bf[t] = *(const short8*)&Bs[(wn + t * 16 + (lane & 15)) * 32 + (lane >> 4) * 8];
        }
#pragma unroll
        for (int i = 0; i < 4; i++)
#pragma unroll
            for (int j = 0; j < 4; j++)
                acc[i][j] = __builtin_amdgcn_mfma_f32_16x16x32_bf16(af[i], bf[j], acc[i][j], 0, 0, 0);
    }

    const int cr = (lane >> 4) * 4;
    const int cc = lane & 15;
    if constexpr (OUTMODE == 0) {
        unsigned short* o = (unsigned short*)outp;
#pragma unroll
        for (int i = 0; i < 4; i++)
#pragma unroll
            for (int j = 0; j < 4; j++) {
                int col = n0 + wn + j * 16 + cc;
#pragma unroll
                for (int r = 0; r < 4; r++) {
                    int row = m0 + wm + i * 16 + cr + r;
                    o[(size_t)row * N + col] = f2b(acc[i][j][r]);
                }
            }
    } else {
        float* o = (float*)outp;
#pragma unroll
        for (int j = 0; j < 4; j++) {
            int col = n0 + wn + j * 16 + cc;
            if (col < ncols) {
                float bv = bias[col];
#pragma unroll
                for (int i = 0; i < 4; i++)
#pragma unroll
                    for (int r = 0; r < 4; r++) {
                        int row = m0 + wm + i * 16 + cr + r;
                        o[(size_t)row * ncols + col] = acc[i][j][r] + bv;
                    }
            }
        }
    }
}

// ---------------- recurrent GEMM 1 (hp only): hp = h @ W_h2h^T + b_h2h -----------
// Direct-from-global MFMA fragments (no LDS, no barriers). Wave tile 16x16.
// grid (8,16) = 128 blocks, 256 thr = 4 waves. (gh moved into attn dispatch.)
__global__ __launch_bounds__(256) void gemm_hp(
    const unsigned short* __restrict__ h16, const unsigned short* __restrict__ w1,
    const float* __restrict__ b_h2h, float* __restrict__ hp)
{
    const int tid = threadIdx.x, lane = tid & 63, wv = tid >> 6;
    const int m0 = blockIdx.y * 16;
    const int n0 = blockIdx.x * 64 + wv * 16;
    const unsigned short* ap = h16 + (size_t)(m0 + (lane & 15)) * H_ + (lane >> 4) * 8;
    const unsigned short* bp = w1 + (size_t)(n0 + (lane & 15)) * H_ + (lane >> 4) * 8;
    f32x4 acc = (f32x4)0.f;
#pragma unroll
    for (int k0 = 0; k0 < H_; k0 += 32) {
        short8 a  = *(const short8*)(ap + k0);
        short8 b0 = *(const short8*)(bp + k0);
        acc = __builtin_amdgcn_mfma_f32_16x16x32_bf16(a, b0, acc, 0, 0, 0);
    }
    const int cc = lane & 15, cr = (lane >> 4) * 4;
    const int col = n0 + cc;
    const float bv = b_h2h[col];
#pragma unroll
    for (int r = 0; r < 4; r++)
        hp[(size_t)(m0 + cr + r) * H_ + col] = acc[r] + bv;
}

// ---------------- fat dispatch: attn (blocks 0..255) || gh GEMM (blocks 256..287) --
// attn: byte-identical R0 body. gh blocks: 32 blocks x 16 waves = 512 wave-units
// computing gh = h @ W_hh^T + b_hh (bitwise-identical accumulation to old gemm_hg).
// gh depends only on h(s-1), is consumed only by gates -> hides under attn.
__global__ __launch_bounds__(1024) void attn_gh(
    const unsigned short* __restrict__ fp, const unsigned short* __restrict__ feats16,
    const float* __restrict__ hp, const float* __restrict__ wscore,
    unsigned short* __restrict__ ctx16,
    const unsigned short* __restrict__ h16, const unsigned short* __restrict__ whh,
    const float* __restrict__ b_hh, float* __restrict__ gh)
{
    const int tid = threadIdx.x, lane = tid & 63, wv = tid >> 6;

    if (blockIdx.x >= B_) {
        // ---- gh part: wave-unit u covers 16x16 tile per gate-triple ----
        const int u = ((int)blockIdx.x - B_) * 16 + wv;     // 0..511
        const int m0 = (u >> 5) * 16;
        const int n0 = (u & 31) * 16;
        const unsigned short* ah = h16 + (size_t)(m0 + (lane & 15)) * H_ + (lane >> 4) * 8;
        const unsigned short* bh = whh + (size_t)(n0 + (lane & 15)) * H_ + (lane >> 4) * 8;
        f32x4 gr = (f32x4)0.f, gz = (f32x4)0.f, gn = (f32x4)0.f;
#pragma unroll
        for (int k0 = 0; k0 < H_; k0 += 32) {
            short8 a   = *(const short8*)(ah + k0);
            short8 cr_ = *(const short8*)(bh + k0);
            short8 cz_ = *(const short8*)(bh + (size_t)512 * H_ + k0);
            short8 cn_ = *(const short8*)(bh + (size_t)1024 * H_ + k0);
            gr = __builtin_amdgcn_mfma_f32_16x16x32_bf16(a, cr_, gr, 0, 0, 0);
            gz = __builtin_amdgcn_mfma_f32_16x16x32_bf16(a, cz_, gz, 0, 0, 0);
            gn = __builtin_amdgcn_mfma_f32_16x16x32_bf16(a, cn_, gn, 0, 0, 0);
        }
        const int cc = lane & 15, cr = (lane >> 4) * 4;
        const int col = n0 + cc;
        const float bhr = b_hh[col], bhz = b_hh[512 + col], bhn = b_hh[1024 + col];
#pragma unroll
        for (int r = 0; r < 4; r++) {
            int row = m0 + cr + r;
            gh[(size_t)row * 1536 + col]        = gr[r] + bhr;
            gh[(size_t)row * 1536 + 512 + col]  = gz[r] + bhz;
            gh[(size_t)row * 1536 + 1024 + col] = gn[r] + bhn;
        }
        return;
    }

    // ---- attn part (R0 body) ----
    const int b = blockIdx.x;
    __shared__ float se[T_];
    __shared__ float ctx4[4][C_];

    float hpr[8], wsr[8];
    {
        const float* hb = hp + b * H_ + lane * 8;
        const float* wb = wscore + lane * 8;
#pragma unroll
        for (int i = 0; i < 8; i++) { hpr[i] = hb[i]; wsr[i] = wb[i]; }
    }
#pragma unroll
    for (int i = 0; i < 8; i++) {           // 16 waves x 8 t = 128
        int t = wv * 8 + i;
        short8 v = *(const short8*)(fp + ((size_t)t * B_ + b) * H_ + lane * 8);
        float p = 0.f;
#pragma unroll
        for (int j = 0; j < 8; j++)
            p += wsr[j] * tanh_fast(b2f((unsigned short)v[j]) + hpr[j]);
#pragma unroll
        for (int off = 32; off > 0; off >>= 1) p += __shfl_xor(p, off, 64);
        if (lane == 0) se[t] = p;
    }
    __syncthreads();
    if (wv == 0) {
        float v0 = se[lane], v1 = se[lane + 64];
        float mx = fmaxf(v0, v1);
#pragma unroll
        for (int off = 32; off > 0; off >>= 1) mx = fmaxf(mx, __shfl_xor(mx, off, 64));
        float e0 = __expf(v0 - mx), e1 = __expf(v1 - mx);
        float s = e0 + e1;
#pragma unroll
        for (int off = 32; off > 0; off >>= 1) s += __shfl_xor(s, off, 64);
        float inv = 1.f / s;
        se[lane] = e0 * inv; se[lane + 64] = e1 * inv;
    }
    __syncthreads();
    // context: thread handles 2 adjacent c, quarter of the t-range
    const int c = (tid & 255) * 2;
    const int q = tid >> 8;                 // 0..3
    float a0 = 0.f, a1 = 0.f;
    const unsigned short* fb = feats16 + (size_t)b * C_ + c;
    for (int i = 0; i < 32; i++) {
        int t = q * 32 + i;
        float al = se[t];
        unsigned int u = *(const unsigned int*)(fb + (size_t)t * B_ * C_);
        a0 += al * b2f((unsigned short)(u & 0xffffu));
        a1 += al * b2f((unsigned short)(u >> 16));
    }
    ctx4[q][c] = a0; ctx4[q][c + 1] = a1;
    __syncthreads();
    if (tid < C_) {
        float s = ctx4[0][tid] + ctx4[1][tid] + ctx4[2][tid] + ctx4[3][tid];
        ctx16[(size_t)b * C_ + tid] = f2b(s);
    }
}

// ---------------- recurrent GEMM 2 + GRU gates fused -----------------------------
// gi = ctx @ W_ih^T (3 gate accumulators per tile), epilogue applies gates,
// writes h32/h16/outH. Wave tile 16x16x3gates. grid (512/64, 256/16) = (8,16).
__global__ __launch_bounds__(256) void gemm_gates(
    const unsigned short* __restrict__ ctx, const unsigned short* __restrict__ wih,
    const float* __restrict__ gh, const float* __restrict__ b_ih,
    const float* __restrict__ hin32, float* __restrict__ hout32,
    unsigned short* __restrict__ hout16, unsigned short* __restrict__ outH, int step)
{
    const int tid = threadIdx.x, lane = tid & 63, wv = tid >> 6;
    const int m0 = blockIdx.y * 16;
    const int n0 = blockIdx.x * 64 + wv * 16;
    const unsigned short* ap = ctx + (size_t)(m0 + (lane & 15)) * C_ + (lane >> 4) * 8;
    const unsigned short* bp = wih + (size_t)(n0 + (lane & 15)) * H_ + (lane >> 4) * 8;
    f32x4 ar = (f32x4)0.f, az = (f32x4)0.f, an = (f32x4)0.f;
#pragma unroll
    for (int k0 = 0; k0 < H_; k0 += 32) {
        short8 a  = *(const short8*)(ap + k0);
        short8 br = *(const short8*)(bp + k0);
        short8 bz = *(const short8*)(bp + (size_t)512 * H_ + k0);
        short8 bn = *(const short8*)(bp + (size_t)1024 * H_ + k0);
        ar = __builtin_amdgcn_mfma_f32_16x16x32_bf16(a, br, ar, 0, 0, 0);
        az = __builtin_amdgcn_mfma_f32_16x16x32_bf16(a, bz, az, 0, 0, 0);
        an = __builtin_amdgcn_mfma_f32_16x16x32_bf16(a, bn, an, 0, 0, 0);
    }
    const int cc = lane & 15, cr = (lane >> 4) * 4;
    const int col = n0 + cc;
    const float br_ = b_ih[col], bz_ = b_ih[512 + col], bn_ = b_ih[1024 + col];
#pragma unroll
    for (int r = 0; r < 4; r++) {
        int row = m0 + cr + r;
        float ghr = gh[(size_t)row * 1536 + col];
        float ghz = gh[(size_t)row * 1536 + 512 + col];
        float ghn = gh[(size_t)row * 1536 + 1024 + col];
        float hv  = hin32[(size_t)row * H_ + col];
        float rg = sigm(ar[r] + br_ + ghr);
        float zg = sigm(az[r] + bz_ + ghz);
        float ng = tanh_fast(an[r] + bn_ + rg * ghn);
        float hn = (1.f - zg) * ng + zg * hv;
        hout32[(size_t)row * H_ + col] = hn;
        unsigned short hb = f2b(hn);
        hout16[(size_t)row * H_ + col] = hb;
        outH[((size_t)row * L_ + step) * H_ + col] = hb;
    }
}

extern "C" void kernel_launch(void* const* d_in, const int* in_sizes, int n_in,
                              void* d_out, int out_size, void* d_ws, size_t ws_size,
                              hipStream_t stream)
{
    const float* feats   = (const float*)d_in[0];
    const float* W_i2h   = (const float*)d_in[2];
    const float* W_h2h   = (const float*)d_in[3];
    const float* b_h2h   = (const float*)d_in[4];
    const float* W_score = (const float*)d_in[5];
    const float* W_ih    = (const float*)d_in[6];
    const float* W_hh    = (const float*)d_in[7];
    const float* b_ih    = (const float*)d_in[8];
    const float* b_hh    = (const float*)d_in[9];
    const float* W_gen   = (const float*)d_in[10];
    const float* b_gen   = (const float*)d_in[11];

    char* ws = (char*)d_ws;
    size_t off = 0;
    auto alloc = [&](size_t bytes) {
        void* p = ws + off; off += (bytes + 255) & ~(size_t)255; return p;
    };
    unsigned short* feats16 = (unsigned short*)alloc((size_t)T_ * B_ * C_ * 2);
    unsigned short* fp16    = (unsigned short*)alloc((size_t)T_ * B_ * H_ * 2);
    unsigned short* wgen16  = (unsigned short*)alloc((size_t)NPAD * H_ * 2);
    unsigned short* wi2h16  = (unsigned short*)alloc((size_t)H_ * C_ * 2);
    unsigned short* w1_16   = (unsigned short*)alloc((size_t)2048 * 512 * 2);
    unsigned short* wih16   = (unsigned short*)alloc((size_t)1536 * 512 * 2);
    unsigned short* outH16  = (unsigned short*)alloc((size_t)B_ * L_ * H_ * 2);
    float* h32a = (float*)alloc((size_t)B_ * H_ * 4);
    float* h32b = (float*)alloc((size_t)B_ * H_ * 4);
    unsigned short* h16a = (unsigned short*)alloc((size_t)B_ * H_ * 2);
    unsigned short* h16b = (unsigned short*)alloc((size_t)B_ * H_ * 2);
    float* hp  = (float*)alloc((size_t)B_ * H_ * 4);
    float* gh  = (float*)alloc((size_t)B_ * 1536 * 4);
    unsigned short* ctx16 = (unsigned short*)alloc((size_t)B_ * C_ * 2);

    prep_kernel<<<dim3((T_ * B_ * C_) / 256), 256, 0, stream>>>(
        feats, W_i2h, W_gen, W_h2h, W_hh, W_ih,
        feats16, wi2h16, wgen16, w1_16, wih16, h32a, h16a);

    // feats_proj = feats @ W_i2h^T  -> bf16 [T*B, H]
    gemm_bt<0><<<dim3(H_ / 128, (T_ * B_) / 128), 256, 0, stream>>>(
        feats16, wi2h16, fp16, nullptr, T_ * B_, H_, C_, 0);

    for (int s = 0; s < L_; s++) {
        const float* hin32          = (s & 1) ? h32b : h32a;
        float* hout32               = (s & 1) ? h32a : h32b;
        const unsigned short* hin16 = (s & 1) ? h16b : h16a;
        unsigned short* hout16      = (s & 1) ? h16a : h16b;
        gemm_hp<<<dim3(8, 16), 256, 0, stream>>>(hin16, w1_16, b_h2h, hp);
        attn_gh<<<dim3(B_ + 32), 1024, 0, stream>>>(
            fp16, feats16, hp, W_score, ctx16,
            hin16, w1_16 + 262144, b_hh, gh);
        gemm_gates<<<dim3(8, 16), 256, 0, stream>>>(
            ctx16, wih16, gh, b_ih, hin32, hout32, hout16, outH16, s);
    }

    // probs = out_h @ W_gen^T + b_gen
    gemm_bt<1><<<dim3(NPAD / 128, (B_ * L_) / 128), 256, 0, stream>>>(
        outH16, wgen16, d_out, b_gen, B_ * L_, NPAD, H_, NCLS);
}

// Round 11
// 1326.814 us; speedup vs baseline: 1.5068x; 1.5068x over previous
//
#include <hip/hip_runtime.h>

#define T_   128
#define B_   256
#define C_   512
#define H_   512
#define L_   26
#define NCLS 6736
#define NPAD 6784   // 53*128, padded N for final GEMM

typedef __attribute__((ext_vector_type(8))) short short8;
typedef __attribute__((ext_vector_type(4))) float f32x4;

__device__ __forceinline__ unsigned short f2b(float f) {
    union { float f; unsigned int u; } v; v.f = f;
    unsigned int r = (v.u + 0x7fffu + ((v.u >> 16) & 1u)) >> 16;
    return (unsigned short)r;
}
__device__ __forceinline__ float b2f(unsigned short u) {
    union { unsigned int u; float f; } v; v.u = ((unsigned int)u) << 16;
    return v.f;
}
__device__ __forceinline__ float tanh_fast(float x) {
    float e = __expf(2.f * x);
    return 1.f - 2.f / (e + 1.f);
}
__device__ __forceinline__ float sigm(float x) {
    return 1.f / (1.f + __expf(-x));
}
__device__ __forceinline__ void llds16(const unsigned short* g, unsigned short* l) {
    __builtin_amdgcn_global_load_lds(
        (const __attribute__((address_space(1))) void*)g,
        (__attribute__((address_space(3))) void*)l, 16, 0, 0);
}
__device__ __forceinline__ void cast8(const float* __restrict__ src,
                                      unsigned short* __restrict__ dst) {
    f32x4 a = *(const f32x4*)src;
    f32x4 b = *(const f32x4*)(src + 4);
    short8 o;
    o[0] = (short)f2b(a[0]); o[1] = (short)f2b(a[1]);
    o[2] = (short)f2b(a[2]); o[3] = (short)f2b(a[3]);
    o[4] = (short)f2b(b[0]); o[5] = (short)f2b(b[1]);
    o[6] = (short)f2b(b[2]); o[7] = (short)f2b(b[3]);
    *(short8*)dst = o;
}

// ---------------- prep: casts + zero-init h (8 elements/thread) ----------------
// All range boundaries are multiples of 8 -> chunks never straddle a source
// switch; per-element rounding identical to the scalar version.
__global__ __launch_bounds__(256) void prep_kernel(
    const float* __restrict__ feats, const float* __restrict__ W_i2h,
    const float* __restrict__ W_gen, const float* __restrict__ W_h2h,
    const float* __restrict__ W_hh, const float* __restrict__ W_ih,
    unsigned short* __restrict__ feats16, unsigned short* __restrict__ wi2h16,
    unsigned short* __restrict__ wgen16, unsigned short* __restrict__ w1_16,
    unsigned short* __restrict__ wih16,
    float* __restrict__ h32, unsigned short* __restrict__ h16)
{
    size_t i8 = ((size_t)blockIdx.x * 256 + threadIdx.x) * 8;   // 16,777,216 elems
    cast8(feats + i8, feats16 + i8);
    if (i8 < (size_t)H_ * C_) cast8(W_i2h + i8, wi2h16 + i8);
    if (i8 < (size_t)NPAD * H_) {
        if (i8 < (size_t)NCLS * H_) cast8(W_gen + i8, wgen16 + i8);   // 3448832 % 8 == 0
        else *(short8*)(wgen16 + i8) = (short8)0;
    }
    if (i8 < (size_t)2048 * 512) {
        if (i8 < 262144) cast8(W_h2h + i8, w1_16 + i8);
        else             cast8(W_hh + (i8 - 262144), w1_16 + i8);
    }
    if (i8 < (size_t)1536 * 512) cast8(W_ih + i8, wih16 + i8);
    if (i8 < (size_t)B_ * H_) {
        *(f32x4*)(h32 + i8)     = (f32x4)0.f;
        *(f32x4*)(h32 + i8 + 4) = (f32x4)0.f;
        *(short8*)(h16 + i8)    = (short8)0;
    }
}

// ---------------- bf16 MFMA GEMM, C = A @ B^T (+bias), XCD swizzle ----------------
template<int OUTMODE>   // 0: bf16 out (ld=N)  1: f32 out + bias + col<ncols guard (ld=ncols)
__global__ __launch_bounds__(256) void gemm_bt(
    const unsigned short* __restrict__ A, const unsigned short* __restrict__ B,
    void* __restrict__ outp, const float* __restrict__ bias,
    int M, int N, int K, int ncols)
{
    __shared__ unsigned short As[128 * 32];
    __shared__ unsigned short Bs[128 * 32];
    const int tid = threadIdx.x;
    const int lane = tid & 63;

    const int gridN = (int)gridDim.x, gridM = (int)gridDim.y;
    const int bid = (int)blockIdx.y * gridN + (int)blockIdx.x;
    const int GM = 8;
    const int per = GM * gridN;
    const int grp = bid / per;
    const int rem = bid - grp * per;
    const int gsz0 = gridM - grp * GM;
    const int gsz = gsz0 < GM ? gsz0 : GM;
    const int m0 = (grp * GM + rem % gsz) * 128;
    const int n0 = (rem / gsz) * 128;

    const int wv = tid >> 6;
    const int wm = (wv >> 1) * 64;
    const int wn = (wv & 1) * 64;

    f32x4 acc[4][4];
#pragma unroll
    for (int i = 0; i < 4; i++)
#pragma unroll
        for (int j = 0; j < 4; j++) acc[i][j] = (f32x4)0.f;

    for (int k0 = 0; k0 < K; k0 += 32) {
        __syncthreads();
#pragma unroll
        for (int is = 0; is < 2; ++is) {
            int c = is * 256 + tid;
            int row = c >> 2, col = (c & 3) * 8;
            llds16(A + (size_t)(m0 + row) * K + k0 + col, &As[c * 8]);
            llds16(B + (size_t)(n0 + row) * K + k0 + col, &Bs[c * 8]);
        }
        __syncthreads();
        short8 af[4], bf[4];
#pragma unroll
        for (int t = 0; t < 4; t++) {
            af[t] = *(const short8*)&As[(wm + t * 16 + (lane & 15)) * 32 + (lane >> 4) * 8];
            bf[t] = *(const short8*)&Bs[(wn + t * 16 + (lane & 15)) * 32 + (lane >> 4) * 8];
        }
#pragma unroll
        for (int i = 0; i < 4; i++)
#pragma unroll
            for (int j = 0; j < 4; j++)
                acc[i][j] = __builtin_amdgcn_mfma_f32_16x16x32_bf16(af[i], bf[j], acc[i][j], 0, 0, 0);
    }

    const int cr = (lane >> 4) * 4;
    const int cc = lane & 15;
    if constexpr (OUTMODE == 0) {
        unsigned short* o = (unsigned short*)outp;
#pragma unroll
        for (int i = 0; i < 4; i++)
#pragma unroll
            for (int j = 0; j < 4; j++) {
                int col = n0 + wn + j * 16 + cc;
#pragma unroll
                for (int r = 0; r < 4; r++) {
                    int row = m0 + wm + i * 16 + cr + r;
                    o[(size_t)row * N + col] = f2b(acc[i][j][r]);
                }
            }
    } else {
        float* o = (float*)outp;
#pragma unroll
        for (int j = 0; j < 4; j++) {
            int col = n0 + wn + j * 16 + cc;
            if (col < ncols) {
                float bv = bias[col];
#pragma unroll
                for (int i = 0; i < 4; i++)
#pragma unroll
                    for (int r = 0; r < 4; r++) {
                        int row = m0 + wm + i * 16 + cr + r;
                        o[(size_t)row * ncols + col] = acc[i][j][r] + bv;
                    }
            }
        }
    }
}

// ---------------- recurrent GEMM 1: [hp | gh] = h @ [W_h2h;W_hh]^T + bias ----------
// Direct-from-global MFMA fragments (no LDS, no barriers). Wave tile 16x32.
// grid (2048/128, 256/16) = (16,16), 256 thr = 4 waves.
__global__ __launch_bounds__(256) void gemm_hg(
    const unsigned short* __restrict__ h16, const unsigned short* __restrict__ w1,
    const float* __restrict__ b_h2h, const float* __restrict__ b_hh,
    float* __restrict__ hp, float* __restrict__ gh)
{
    const int tid = threadIdx.x, lane = tid & 63, wv = tid >> 6;
    const int m0 = blockIdx.y * 16;
    const int n0 = blockIdx.x * 128 + wv * 32;
    const unsigned short* ap = h16 + (size_t)(m0 + (lane & 15)) * H_ + (lane >> 4) * 8;
    const unsigned short* bp = w1 + (size_t)(n0 + (lane & 15)) * H_ + (lane >> 4) * 8;
    f32x4 acc0 = (f32x4)0.f, acc1 = (f32x4)0.f;
#pragma unroll
    for (int k0 = 0; k0 < H_; k0 += 32) {
        short8 a  = *(const short8*)(ap + k0);
        short8 b0 = *(const short8*)(bp + k0);
        short8 b1 = *(const short8*)(bp + (size_t)16 * H_ + k0);
        acc0 = __builtin_amdgcn_mfma_f32_16x16x32_bf16(a, b0, acc0, 0, 0, 0);
        acc1 = __builtin_amdgcn_mfma_f32_16x16x32_bf16(a, b1, acc1, 0, 0, 0);
    }
    const int cc = lane & 15, cr = (lane >> 4) * 4;
#pragma unroll
    for (int j = 0; j < 2; j++) {
        int col = n0 + j * 16 + cc;
        f32x4 av = j ? acc1 : acc0;
        float bv = (col < H_) ? b_h2h[col] : b_hh[col - H_];
#pragma unroll
        for (int r = 0; r < 4; r++) {
            int row = m0 + cr + r;
            float v = av[r] + bv;
            if (col < H_) hp[(size_t)row * H_ + col] = v;
            else          gh[(size_t)row * 1536 + (col - H_)] = v;
        }
    }
}

// ---------------- fused attention: hp -> e -> softmax -> context (bf16) -----------
// One block per b, 1024 threads (16 waves).
__global__ __launch_bounds__(1024) void attn_fused(
    const unsigned short* __restrict__ fp, const unsigned short* __restrict__ feats16,
    const float* __restrict__ hp, const float* __restrict__ wscore,
    unsigned short* __restrict__ ctx16)
{
    const int b = blockIdx.x;
    const int tid = threadIdx.x, lane = tid & 63, wv = tid >> 6;
    __shared__ float se[T_];
    __shared__ float ctx4[4][C_];

    float hpr[8], wsr[8];
    {
        const float* hb = hp + b * H_ + lane * 8;
        const float* wb = wscore + lane * 8;
#pragma unroll
        for (int i = 0; i < 8; i++) { hpr[i] = hb[i]; wsr[i] = wb[i]; }
    }
#pragma unroll
    for (int i = 0; i < 8; i++) {           // 16 waves x 8 t = 128
        int t = wv * 8 + i;
        short8 v = *(const short8*)(fp + ((size_t)t * B_ + b) * H_ + lane * 8);
        float p = 0.f;
#pragma unroll
        for (int j = 0; j < 8; j++)
            p += wsr[j] * tanh_fast(b2f((unsigned short)v[j]) + hpr[j]);
#pragma unroll
        for (int off = 32; off > 0; off >>= 1) p += __shfl_xor(p, off, 64);
        if (lane == 0) se[t] = p;
    }
    __syncthreads();
    if (wv == 0) {
        float v0 = se[lane], v1 = se[lane + 64];
        float mx = fmaxf(v0, v1);
#pragma unroll
        for (int off = 32; off > 0; off >>= 1) mx = fmaxf(mx, __shfl_xor(mx, off, 64));
        float e0 = __expf(v0 - mx), e1 = __expf(v1 - mx);
        float s = e0 + e1;
#pragma unroll
        for (int off = 32; off > 0; off >>= 1) s += __shfl_xor(s, off, 64);
        float inv = 1.f / s;
        se[lane] = e0 * inv; se[lane + 64] = e1 * inv;
    }
    __syncthreads();
    // context: thread handles 2 adjacent c, quarter of the t-range
    const int c = (tid & 255) * 2;
    const int q = tid >> 8;                 // 0..3
    float a0 = 0.f, a1 = 0.f;
    const unsigned short* fb = feats16 + (size_t)b * C_ + c;
    for (int i = 0; i < 32; i++) {
        int t = q * 32 + i;
        float al = se[t];
        unsigned int u = *(const unsigned int*)(fb + (size_t)t * B_ * C_);
        a0 += al * b2f((unsigned short)(u & 0xffffu));
        a1 += al * b2f((unsigned short)(u >> 16));
    }
    ctx4[q][c] = a0; ctx4[q][c + 1] = a1;
    __syncthreads();
    if (tid < C_) {
        float s = ctx4[0][tid] + ctx4[1][tid] + ctx4[2][tid] + ctx4[3][tid];
        ctx16[(size_t)b * C_ + tid] = f2b(s);
    }
}

// ---------------- recurrent GEMM 2 + GRU gates fused -----------------------------
// gi = ctx @ W_ih^T (3 gate accumulators per tile), epilogue applies gates,
// writes h32/h16/outH. Wave tile 16x16x3gates. grid (512/64, 256/16) = (8,16).
__global__ __launch_bounds__(256) void gemm_gates(
    const unsigned short* __restrict__ ctx, const unsigned short* __restrict__ wih,
    const float* __restrict__ gh, const float* __restrict__ b_ih,
    const float* __restrict__ hin32, float* __restrict__ hout32,
    unsigned short* __restrict__ hout16, unsigned short* __restrict__ outH, int step)
{
    const int tid = threadIdx.x, lane = tid & 63, wv = tid >> 6;
    const int m0 = blockIdx.y * 16;
    const int n0 = blockIdx.x * 64 + wv * 16;
    const unsigned short* ap = ctx + (size_t)(m0 + (lane & 15)) * C_ + (lane >> 4) * 8;
    const unsigned short* bp = wih + (size_t)(n0 + (lane & 15)) * H_ + (lane >> 4) * 8;
    f32x4 ar = (f32x4)0.f, az = (f32x4)0.f, an = (f32x4)0.f;
#pragma unroll
    for (int k0 = 0; k0 < H_; k0 += 32) {
        short8 a  = *(const short8*)(ap + k0);
        short8 br = *(const short8*)(bp + k0);
        short8 bz = *(const short8*)(bp + (size_t)512 * H_ + k0);
        short8 bn = *(const short8*)(bp + (size_t)1024 * H_ + k0);
        ar = __builtin_amdgcn_mfma_f32_16x16x32_bf16(a, br, ar, 0, 0, 0);
        az = __builtin_amdgcn_mfma_f32_16x16x32_bf16(a, bz, az, 0, 0, 0);
        an = __builtin_amdgcn_mfma_f32_16x16x32_bf16(a, bn, an, 0, 0, 0);
    }
    const int cc = lane & 15, cr = (lane >> 4) * 4;
    const int col = n0 + cc;
    const float br_ = b_ih[col], bz_ = b_ih[512 + col], bn_ = b_ih[1024 + col];
#pragma unroll
    for (int r = 0; r < 4; r++) {
        int row = m0 + cr + r;
        float ghr = gh[(size_t)row * 1536 + col];
        float ghz = gh[(size_t)row * 1536 + 512 + col];
        float ghn = gh[(size_t)row * 1536 + 1024 + col];
        float hv  = hin32[(size_t)row * H_ + col];
        float rg = sigm(ar[r] + br_ + ghr);
        float zg = sigm(az[r] + bz_ + ghz);
        float ng = tanh_fast(an[r] + bn_ + rg * ghn);
        float hn = (1.f - zg) * ng + zg * hv;
        hout32[(size_t)row * H_ + col] = hn;
        unsigned short hb = f2b(hn);
        hout16[(size_t)row * H_ + col] = hb;
        outH[((size_t)row * L_ + step) * H_ + col] = hb;
    }
}

extern "C" void kernel_launch(void* const* d_in, const int* in_sizes, int n_in,
                              void* d_out, int out_size, void* d_ws, size_t ws_size,
                              hipStream_t stream)
{
    const float* feats   = (const float*)d_in[0];
    const float* W_i2h   = (const float*)d_in[2];
    const float* W_h2h   = (const float*)d_in[3];
    const float* b_h2h   = (const float*)d_in[4];
    const float* W_score = (const float*)d_in[5];
    const float* W_ih    = (const float*)d_in[6];
    const float* W_hh    = (const float*)d_in[7];
    const float* b_ih    = (const float*)d_in[8];
    const float* b_hh    = (const float*)d_in[9];
    const float* W_gen   = (const float*)d_in[10];
    const float* b_gen   = (const float*)d_in[11];

    char* ws = (char*)d_ws;
    size_t off = 0;
    auto alloc = [&](size_t bytes) {
        void* p = ws + off; off += (bytes + 255) & ~(size_t)255; return p;
    };
    unsigned short* feats16 = (unsigned short*)alloc((size_t)T_ * B_ * C_ * 2);
    unsigned short* fp16    = (unsigned short*)alloc((size_t)T_ * B_ * H_ * 2);
    unsigned short* wgen16  = (unsigned short*)alloc((size_t)NPAD * H_ * 2);
    unsigned short* wi2h16  = (unsigned short*)alloc((size_t)H_ * C_ * 2);
    unsigned short* w1_16   = (unsigned short*)alloc((size_t)2048 * 512 * 2);
    unsigned short* wih16   = (unsigned short*)alloc((size_t)1536 * 512 * 2);
    unsigned short* outH16  = (unsigned short*)alloc((size_t)B_ * L_ * H_ * 2);
    float* h32a = (float*)alloc((size_t)B_ * H_ * 4);
    float* h32b = (float*)alloc((size_t)B_ * H_ * 4);
    unsigned short* h16a = (unsigned short*)alloc((size_t)B_ * H_ * 2);
    unsigned short* h16b = (unsigned short*)alloc((size_t)B_ * H_ * 2);
    float* hp  = (float*)alloc((size_t)B_ * H_ * 4);
    float* gh  = (float*)alloc((size_t)B_ * 1536 * 4);
    unsigned short* ctx16 = (unsigned short*)alloc((size_t)B_ * C_ * 2);

    prep_kernel<<<dim3((T_ * B_ * C_) / (256 * 8)), 256, 0, stream>>>(
        feats, W_i2h, W_gen, W_h2h, W_hh, W_ih,
        feats16, wi2h16, wgen16, w1_16, wih16, h32a, h16a);

    // feats_proj = feats @ W_i2h^T  -> bf16 [T*B, H]
    gemm_bt<0><<<dim3(H_ / 128, (T_ * B_) / 128), 256, 0, stream>>>(
        feats16, wi2h16, fp16, nullptr, T_ * B_, H_, C_, 0);

    for (int s = 0; s < L_; s++) {
        const float* hin32          = (s & 1) ? h32b : h32a;
        float* hout32               = (s & 1) ? h32a : h32b;
        const unsigned short* hin16 = (s & 1) ? h16b : h16a;
        unsigned short* hout16      = (s & 1) ? h16a : h16b;
        gemm_hg<<<dim3(16, 16), 256, 0, stream>>>(hin16, w1_16, b_h2h, b_hh, hp, gh);
        attn_fused<<<dim3(B_), 1024, 0, stream>>>(fp16, feats16, hp, W_score, ctx16);
        gemm_gates<<<dim3(8, 16), 256, 0, stream>>>(
            ctx16, wih16, gh, b_ih, hin32, hout32, hout16, outH16, s);
    }

    // probs = out_h @ W_gen^T + b_gen
    gemm_bt<1><<<dim3(NPAD / 128, (B_ * L_) / 128), 256, 0, stream>>>(
        outH16, wgen16, d_out, b_gen, B_ * L_, NPAD, H_, NCLS);
}

// Round 12
// 1316.394 us; speedup vs baseline: 1.5187x; 1.0079x over previous
//
#include <hip/hip_runtime.h>

#define T_   128
#define B_   256
#define C_   512
#define H_   512
#define L_   26
#define NCLS 6736
#define NPAD 6784   // 53*128, padded N for final GEMM

typedef __attribute__((ext_vector_type(8))) short short8;
typedef __attribute__((ext_vector_type(4))) float f32x4;

__device__ __forceinline__ unsigned short f2b(float f) {
    union { float f; unsigned int u; } v; v.f = f;
    unsigned int r = (v.u + 0x7fffu + ((v.u >> 16) & 1u)) >> 16;
    return (unsigned short)r;
}
__device__ __forceinline__ float b2f(unsigned short u) {
    union { unsigned int u; float f; } v; v.u = ((unsigned int)u) << 16;
    return v.f;
}
__device__ __forceinline__ float tanh_fast(float x) {
    float e = __expf(2.f * x);
    return 1.f - 2.f / (e + 1.f);
}
__device__ __forceinline__ float sigm(float x) {
    return 1.f / (1.f + __expf(-x));
}
__device__ __forceinline__ void llds16(const unsigned short* g, unsigned short* l) {
    __builtin_amdgcn_global_load_lds(
        (const __attribute__((address_space(1))) void*)g,
        (__attribute__((address_space(3))) void*)l, 16, 0, 0);
}
__device__ __forceinline__ void cast8(const float* __restrict__ src,
                                      unsigned short* __restrict__ dst) {
    f32x4 a = *(const f32x4*)src;
    f32x4 b = *(const f32x4*)(src + 4);
    short8 o;
    o[0] = (short)f2b(a[0]); o[1] = (short)f2b(a[1]);
    o[2] = (short)f2b(a[2]); o[3] = (short)f2b(a[3]);
    o[4] = (short)f2b(b[0]); o[5] = (short)f2b(b[1]);
    o[6] = (short)f2b(b[2]); o[7] = (short)f2b(b[3]);
    *(short8*)dst = o;
}

// ---------------- prep: casts + zero-init h (8 elements/thread) ----------------
// feats is written TRANSPOSED to [B][T][C]: attn block b then streams contiguous
// 128KB regions, and the feats_proj GEMM emits fp16 in [B][T][H] for free.
// All range boundaries are multiples of 8 -> chunks never straddle a source
// switch; per-element rounding identical to the scalar version.
__global__ __launch_bounds__(256) void prep_kernel(
    const float* __restrict__ feats, const float* __restrict__ W_i2h,
    const float* __restrict__ W_gen, const float* __restrict__ W_h2h,
    const float* __restrict__ W_hh, const float* __restrict__ W_ih,
    unsigned short* __restrict__ feats16T, unsigned short* __restrict__ wi2h16,
    unsigned short* __restrict__ wgen16, unsigned short* __restrict__ w1_16,
    unsigned short* __restrict__ wih16,
    float* __restrict__ h32, unsigned short* __restrict__ h16)
{
    size_t i8 = ((size_t)blockIdx.x * 256 + threadIdx.x) * 8;   // 16,777,216 elems
    {
        // i8 = (t*B + b)*C + c  ->  out at (b*T + t)*C + c   (c 8-aligned)
        unsigned t = (unsigned)(i8 >> 17);
        unsigned b = (unsigned)(i8 >> 9) & 255u;
        unsigned c = (unsigned)i8 & 511u;
        cast8(feats + i8, feats16T + (((size_t)b << 16) + ((size_t)t << 9) + c));
    }
    if (i8 < (size_t)H_ * C_) cast8(W_i2h + i8, wi2h16 + i8);
    if (i8 < (size_t)NPAD * H_) {
        if (i8 < (size_t)NCLS * H_) cast8(W_gen + i8, wgen16 + i8);   // 3448832 % 8 == 0
        else *(short8*)(wgen16 + i8) = (short8)0;
    }
    if (i8 < (size_t)2048 * 512) {
        if (i8 < 262144) cast8(W_h2h + i8, w1_16 + i8);
        else             cast8(W_hh + (i8 - 262144), w1_16 + i8);
    }
    if (i8 < (size_t)1536 * 512) cast8(W_ih + i8, wih16 + i8);
    if (i8 < (size_t)B_ * H_) {
        *(f32x4*)(h32 + i8)     = (f32x4)0.f;
        *(f32x4*)(h32 + i8 + 4) = (f32x4)0.f;
        *(short8*)(h16 + i8)    = (short8)0;
    }
}

// ---------------- bf16 MFMA GEMM, C = A @ B^T (+bias), XCD swizzle ----------------
template<int OUTMODE>   // 0: bf16 out (ld=N)  1: f32 out + bias + col<ncols guard (ld=ncols)
__global__ __launch_bounds__(256) void gemm_bt(
    const unsigned short* __restrict__ A, const unsigned short* __restrict__ B,
    void* __restrict__ outp, const float* __restrict__ bias,
    int M, int N, int K, int ncols)
{
    __shared__ unsigned short As[128 * 32];
    __shared__ unsigned short Bs[128 * 32];
    const int tid = threadIdx.x;
    const int lane = tid & 63;

    const int gridN = (int)gridDim.x, gridM = (int)gridDim.y;
    const int bid = (int)blockIdx.y * gridN + (int)blockIdx.x;
    const int GM = 8;
    const int per = GM * gridN;
    const int grp = bid / per;
    const int rem = bid - grp * per;
    const int gsz0 = gridM - grp * GM;
    const int gsz = gsz0 < GM ? gsz0 : GM;
    const int m0 = (grp * GM + rem % gsz) * 128;
    const int n0 = (rem / gsz) * 128;

    const int wv = tid >> 6;
    const int wm = (wv >> 1) * 64;
    const int wn = (wv & 1) * 64;

    f32x4 acc[4][4];
#pragma unroll
    for (int i = 0; i < 4; i++)
#pragma unroll
        for (int j = 0; j < 4; j++) acc[i][j] = (f32x4)0.f;

    for (int k0 = 0; k0 < K; k0 += 32) {
        __syncthreads();
#pragma unroll
        for (int is = 0; is < 2; ++is) {
            int c = is * 256 + tid;
            int row = c >> 2, col = (c & 3) * 8;
            llds16(A + (size_t)(m0 + row) * K + k0 + col, &As[c * 8]);
            llds16(B + (size_t)(n0 + row) * K + k0 + col, &Bs[c * 8]);
        }
        __syncthreads();
        short8 af[4], bf[4];
#pragma unroll
        for (int t = 0; t < 4; t++) {
            af[t] = *(const short8*)&As[(wm + t * 16 + (lane & 15)) * 32 + (lane >> 4) * 8];
            bf[t] = *(const short8*)&Bs[(wn + t * 16 + (lane & 15)) * 32 + (lane >> 4) * 8];
        }
#pragma unroll
        for (int i = 0; i < 4; i++)
#pragma unroll
            for (int j = 0; j < 4; j++)
                acc[i][j] = __builtin_amdgcn_mfma_f32_16x16x32_bf16(af[i], bf[j], acc[i][j], 0, 0, 0);
    }

    const int cr = (lane >> 4) * 4;
    const int cc = lane & 15;
    if constexpr (OUTMODE == 0) {
        unsigned short* o = (unsigned short*)outp;
#pragma unroll
        for (int i = 0; i < 4; i++)
#pragma unroll
            for (int j = 0; j < 4; j++) {
                int col = n0 + wn + j * 16 + cc;
#pragma unroll
                for (int r = 0; r < 4; r++) {
                    int row = m0 + wm + i * 16 + cr + r;
                    o[(size_t)row * N + col] = f2b(acc[i][j][r]);
                }
            }
    } else {
        float* o = (float*)outp;
#pragma unroll
        for (int j = 0; j < 4; j++) {
            int col = n0 + wn + j * 16 + cc;
            if (col < ncols) {
                float bv = bias[col];
#pragma unroll
                for (int i = 0; i < 4; i++)
#pragma unroll
                    for (int r = 0; r < 4; r++) {
                        int row = m0 + wm + i * 16 + cr + r;
                        o[(size_t)row * ncols + col] = acc[i][j][r] + bv;
                    }
            }
        }
    }
}

// ---------------- recurrent GEMM 1: [hp | gh] = h @ [W_h2h;W_hh]^T + bias ----------
// Direct-from-global MFMA fragments (no LDS, no barriers). Wave tile 16x32.
// grid (2048/128, 256/16) = (16,16), 256 thr = 4 waves.
__global__ __launch_bounds__(256) void gemm_hg(
    const unsigned short* __restrict__ h16, const unsigned short* __restrict__ w1,
    const float* __restrict__ b_h2h, const float* __restrict__ b_hh,
    float* __restrict__ hp, float* __restrict__ gh)
{
    const int tid = threadIdx.x, lane = tid & 63, wv = tid >> 6;
    const int m0 = blockIdx.y * 16;
    const int n0 = blockIdx.x * 128 + wv * 32;
    const unsigned short* ap = h16 + (size_t)(m0 + (lane & 15)) * H_ + (lane >> 4) * 8;
    const unsigned short* bp = w1 + (size_t)(n0 + (lane & 15)) * H_ + (lane >> 4) * 8;
    f32x4 acc0 = (f32x4)0.f, acc1 = (f32x4)0.f;
#pragma unroll
    for (int k0 = 0; k0 < H_; k0 += 32) {
        short8 a  = *(const short8*)(ap + k0);
        short8 b0 = *(const short8*)(bp + k0);
        short8 b1 = *(const short8*)(bp + (size_t)16 * H_ + k0);
        acc0 = __builtin_amdgcn_mfma_f32_16x16x32_bf16(a, b0, acc0, 0, 0, 0);
        acc1 = __builtin_amdgcn_mfma_f32_16x16x32_bf16(a, b1, acc1, 0, 0, 0);
    }
    const int cc = lane & 15, cr = (lane >> 4) * 4;
#pragma unroll
    for (int j = 0; j < 2; j++) {
        int col = n0 + j * 16 + cc;
        f32x4 av = j ? acc1 : acc0;
        float bv = (col < H_) ? b_h2h[col] : b_hh[col - H_];
#pragma unroll
        for (int r = 0; r < 4; r++) {
            int row = m0 + cr + r;
            float v = av[r] + bv;
            if (col < H_) hp[(size_t)row * H_ + col] = v;
            else          gh[(size_t)row * 1536 + (col - H_)] = v;
        }
    }
}

// ---------------- fused attention: hp -> e -> softmax -> context (bf16) -----------
// One block per b, 1024 threads (16 waves). fp/feats in [B][T][*] layout:
// block b streams two contiguous 128KB regions.
__global__ __launch_bounds__(1024) void attn_fused(
    const unsigned short* __restrict__ fp, const unsigned short* __restrict__ feats16T,
    const float* __restrict__ hp, const float* __restrict__ wscore,
    unsigned short* __restrict__ ctx16)
{
    const int b = blockIdx.x;
    const int tid = threadIdx.x, lane = tid & 63, wv = tid >> 6;
    __shared__ float se[T_];
    __shared__ float ctx4[4][C_];

    float hpr[8], wsr[8];
    {
        const float* hb = hp + b * H_ + lane * 8;
        const float* wb = wscore + lane * 8;
#pragma unroll
        for (int i = 0; i < 8; i++) { hpr[i] = hb[i]; wsr[i] = wb[i]; }
    }
    const unsigned short* fpb = fp + ((size_t)b << 16);     // b*T*H
#pragma unroll
    for (int i = 0; i < 8; i++) {           // 16 waves x 8 t = 128
        int t = wv * 8 + i;
        short8 v = *(const short8*)(fpb + ((size_t)t << 9) + lane * 8);
        float p = 0.f;
#pragma unroll
        for (int j = 0; j < 8; j++)
            p += wsr[j] * tanh_fast(b2f((unsigned short)v[j]) + hpr[j]);
#pragma unroll
        for (int off = 32; off > 0; off >>= 1) p += __shfl_xor(p, off, 64);
        if (lane == 0) se[t] = p;
    }
    __syncthreads();
    if (wv == 0) {
        float v0 = se[lane], v1 = se[lane + 64];
        float mx = fmaxf(v0, v1);
#pragma unroll
        for (int off = 32; off > 0; off >>= 1) mx = fmaxf(mx, __shfl_xor(mx, off, 64));
        float e0 = __expf(v0 - mx), e1 = __expf(v1 - mx);
        float s = e0 + e1;
#pragma unroll
        for (int off = 32; off > 0; off >>= 1) s += __shfl_xor(s, off, 64);
        float inv = 1.f / s;
        se[lane] = e0 * inv; se[lane + 64] = e1 * inv;
    }
    __syncthreads();
    // context: thread handles 2 adjacent c, quarter of the t-range
    const int c = (tid & 255) * 2;
    const int q = tid >> 8;                 // 0..3
    float a0 = 0.f, a1 = 0.f;
    const unsigned short* fb = feats16T + ((size_t)b << 16) + c;   // b*T*C
    for (int i = 0; i < 32; i++) {
        int t = q * 32 + i;
        float al = se[t];
        unsigned int u = *(const unsigned int*)(fb + ((size_t)t << 9));
        a0 += al * b2f((unsigned short)(u & 0xffffu));
        a1 += al * b2f((unsigned short)(u >> 16));
    }
    ctx4[q][c] = a0; ctx4[q][c + 1] = a1;
    __syncthreads();
    if (tid < C_) {
        float s = ctx4[0][tid] + ctx4[1][tid] + ctx4[2][tid] + ctx4[3][tid];
        ctx16[(size_t)b * C_ + tid] = f2b(s);
    }
}

// ---------------- recurrent GEMM 2 + GRU gates fused -----------------------------
// gi = ctx @ W_ih^T (3 gate accumulators per tile), epilogue applies gates,
// writes h32/h16/outH. Wave tile 16x16x3gates. grid (512/64, 256/16) = (8,16).
__global__ __launch_bounds__(256) void gemm_gates(
    const unsigned short* __restrict__ ctx, const unsigned short* __restrict__ wih,
    const float* __restrict__ gh, const float* __restrict__ b_ih,
    const float* __restrict__ hin32, float* __restrict__ hout32,
    unsigned short* __restrict__ hout16, unsigned short* __restrict__ outH, int step)
{
    const int tid = threadIdx.x, lane = tid & 63, wv = tid >> 6;
    const int m0 = blockIdx.y * 16;
    const int n0 = blockIdx.x * 64 + wv * 16;
    const unsigned short* ap = ctx + (size_t)(m0 + (lane & 15)) * C_ + (lane >> 4) * 8;
    const unsigned short* bp = wih + (size_t)(n0 + (lane & 15)) * H_ + (lane >> 4) * 8;
    f32x4 ar = (f32x4)0.f, az = (f32x4)0.f, an = (f32x4)0.f;
#pragma unroll
    for (int k0 = 0; k0 < H_; k0 += 32) {
        short8 a  = *(const short8*)(ap + k0);
        short8 br = *(const short8*)(bp + k0);
        short8 bz = *(const short8*)(bp + (size_t)512 * H_ + k0);
        short8 bn = *(const short8*)(bp + (size_t)1024 * H_ + k0);
        ar = __builtin_amdgcn_mfma_f32_16x16x32_bf16(a, br, ar, 0, 0, 0);
        az = __builtin_amdgcn_mfma_f32_16x16x32_bf16(a, bz, az, 0, 0, 0);
        an = __builtin_amdgcn_mfma_f32_16x16x32_bf16(a, bn, an, 0, 0, 0);
    }
    const int cc = lane & 15, cr = (lane >> 4) * 4;
    const int col = n0 + cc;
    const float br_ = b_ih[col], bz_ = b_ih[512 + col], bn_ = b_ih[1024 + col];
#pragma unroll
    for (int r = 0; r < 4; r++) {
        int row = m0 + cr + r;
        float ghr = gh[(size_t)row * 1536 + col];
        float ghz = gh[(size_t)row * 1536 + 512 + col];
        float ghn = gh[(size_t)row * 1536 + 1024 + col];
        float hv  = hin32[(size_t)row * H_ + col];
        float rg = sigm(ar[r] + br_ + ghr);
        float zg = sigm(az[r] + bz_ + ghz);
        float ng = tanh_fast(an[r] + bn_ + rg * ghn);
        float hn = (1.f - zg) * ng + zg * hv;
        hout32[(size_t)row * H_ + col] = hn;
        unsigned short hb = f2b(hn);
        hout16[(size_t)row * H_ + col] = hb;
        outH[((size_t)row * L_ + step) * H_ + col] = hb;
    }
}

extern "C" void kernel_launch(void* const* d_in, const int* in_sizes, int n_in,
                              void* d_out, int out_size, void* d_ws, size_t ws_size,
                              hipStream_t stream)
{
    const float* feats   = (const float*)d_in[0];
    const float* W_i2h   = (const float*)d_in[2];
    const float* W_h2h   = (const float*)d_in[3];
    const float* b_h2h   = (const float*)d_in[4];
    const float* W_score = (const float*)d_in[5];
    const float* W_ih    = (const float*)d_in[6];
    const float* W_hh    = (const float*)d_in[7];
    const float* b_ih    = (const float*)d_in[8];
    const float* b_hh    = (const float*)d_in[9];
    const float* W_gen   = (const float*)d_in[10];
    const float* b_gen   = (const float*)d_in[11];

    char* ws = (char*)d_ws;
    size_t off = 0;
    auto alloc = [&](size_t bytes) {
        void* p = ws + off; off += (bytes + 255) & ~(size_t)255; return p;
    };
    unsigned short* feats16T = (unsigned short*)alloc((size_t)T_ * B_ * C_ * 2);
    unsigned short* fp16    = (unsigned short*)alloc((size_t)T_ * B_ * H_ * 2);
    unsigned short* wgen16  = (unsigned short*)alloc((size_t)NPAD * H_ * 2);
    unsigned short* wi2h16  = (unsigned short*)alloc((size_t)H_ * C_ * 2);
    unsigned short* w1_16   = (unsigned short*)alloc((size_t)2048 * 512 * 2);
    unsigned short* wih16   = (unsigned short*)alloc((size_t)1536 * 512 * 2);
    unsigned short* outH16  = (unsigned short*)alloc((size_t)B_ * L_ * H_ * 2);
    float* h32a = (float*)alloc((size_t)B_ * H_ * 4);
    float* h32b = (float*)alloc((size_t)B_ * H_ * 4);
    unsigned short* h16a = (unsigned short*)alloc((size_t)B_ * H_ * 2);
    unsigned short* h16b = (unsigned short*)alloc((size_t)B_ * H_ * 2);
    float* hp  = (float*)alloc((size_t)B_ * H_ * 4);
    float* gh  = (float*)alloc((size_t)B_ * 1536 * 4);
    unsigned short* ctx16 = (unsigned short*)alloc((size_t)B_ * C_ * 2);

    prep_kernel<<<dim3((T_ * B_ * C_) / (256 * 8)), 256, 0, stream>>>(
        feats, W_i2h, W_gen, W_h2h, W_hh, W_ih,
        feats16T, wi2h16, wgen16, w1_16, wih16, h32a, h16a);

    // feats_proj: A = feats16T [B*T, C] -> fp16 [B][T][H] (row permutation, free)
    gemm_bt<0><<<dim3(H_ / 128, (T_ * B_) / 128), 256, 0, stream>>>(
        feats16T, wi2h16, fp16, nullptr, T_ * B_, H_, C_, 0);

    for (int s = 0; s < L_; s++) {
        const float* hin32          = (s & 1) ? h32b : h32a;
        float* hout32               = (s & 1) ? h32a : h32b;
        const unsigned short* hin16 = (s & 1) ? h16b : h16a;
        unsigned short* hout16      = (s & 1) ? h16a : h16b;
        gemm_hg<<<dim3(16, 16), 256, 0, stream>>>(hin16, w1_16, b_h2h, b_hh, hp, gh);
        attn_fused<<<dim3(B_), 1024, 0, stream>>>(fp16, feats16T, hp, W_score, ctx16);
        gemm_gates<<<dim3(8, 16), 256, 0, stream>>>(
            ctx16, wih16, gh, b_ih, hin32, hout32, hout16, outH16, s);
    }

    // probs = out_h @ W_gen^T + b_gen
    gemm_bt<1><<<dim3(NPAD / 128, (B_ * L_) / 128), 256, 0, stream>>>(
        outH16, wgen16, d_out, b_gen, B_ * L_, NPAD, H_, NCLS);
}